// Round 3
// baseline (145.107 us; speedup 1.0000x reference)
//
#include <hip/hip_runtime.h>

// SSIM (7x7 uniform window) over B=64, C=1, H=W=384 fp32 images.
// out = mean over interior 378x378 crop of all 64 images (scalar).
//
// R15 = single-drain staging. Timing decomposition (R13/R14): timed region =
// 2 harness poison fills (83us, fixed) + our kernels, gap-free; ssim ~= 44.8us
// vs ~13us BW floor. Theory: LLVM's waitcnt pass is conservative over LDS for
// global_load_lds DMA -> the R12/R14 interleave (stage(c+2) issued before
// compute(c+1)) forces s_waitcnt vmcnt(0) before EVERY compute phase, draining
// the prefetch each time; all waves drain in lockstep -> ~1.7TB/s sawtooth.
// Fix: issue ALL 42 row-DMAs up front, pay ONE drain, then compute the whole
// band from LDS with zero further vmcnt waits. Band resized so the full slab
// fits LDS at useful occupancy:
//   BAND 15 -> 21 staged rows x 544B x 2 arrays = 22.8KB -> 7 blocks/CU
//   grid 3 tiles x 26 bands x 64 imgs = 4992 blocks (~2.8 batches/CU; later
//   blocks' staging overlaps earlier blocks' compute = block-level pipeline).
// Compute: 'unroll 1' over 3 groups x 7 fully-unrolled rows (ring slot = j
// compile-time, rule #20; ~8KB text).
//
// K1 max_kernel: max(gt) -> ws_max (monotone-encoded uint, atomicMax)
// K2 ssim_kernel: 4992 single-wave blocks, single-drain staging
// K3 final_kernel: sum partials, divide, store d_out[0]
//
// BANNED (measured): coop grid.sync fusion (R13, +192us latency collapse);
// 12B global_load_lds (R10, absmax 0.21); VGPR cap via launch_bounds
// min-waves (R4, 33MB spill); per-block __threadfence finalize (R3/R5 VALU
// collapse); scalar 1col/thread taps (R8, LDS-issue bound).

#define PADW 3
#define BT 64             // threads per block (1 wave); 63 compute 2 cols each
#define BAND 15           // output rows per block
#define SROWS (BAND + 6)  // 21 staged rows = 3 x 7

constexpr int B_ = 64, H_ = 384, W_ = 384;
constexpr int W2 = W_ / 2;                                // row length in float2
constexpr int OUTD = W_ - 2 * PADW;                       // 378
constexpr int NBANDS = (OUTD + BAND - 1) / BAND;          // 26
constexpr int NTILES = 3;                                 // 3 x 126 cols = 378
constexpr int TOTAL_BLOCKS = NTILES * NBANDS * B_;        // 4992
constexpr double NPIX = (double)B_ * OUTD * OUTD;         // 9,144,576

__device__ __forceinline__ unsigned enc_f(float f) {
    unsigned u = __float_as_uint(f);
    return (u & 0x80000000u) ? ~u : (u | 0x80000000u);
}
__device__ __forceinline__ float dec_f(unsigned e) {
    return __uint_as_float((e & 0x80000000u) ? (e & 0x7fffffffu) : ~e);
}

__device__ __forceinline__ float2 f2add(float2 a, float2 b) { return make_float2(a.x + b.x, a.y + b.y); }
__device__ __forceinline__ float2 f2sub(float2 a, float2 b) { return make_float2(a.x - b.x, a.y - b.y); }

// async global->LDS, 16B per lane (global_load_lds_dwordx4, m97-verified):
// lane L loads g[+16L] -> ldsbase + 16L. Pass the WAVE-UNIFORM lds row base.
__device__ __forceinline__ void glds16(const void* g, void* l) {
    __builtin_amdgcn_global_load_lds(
        (const __attribute__((address_space(1))) void*)g,
        (__attribute__((address_space(3))) void*)l, 16, 0, 0);
}

__global__ void __launch_bounds__(256)
max_kernel(const float4* __restrict__ g4, unsigned* ws_max, int n4) {
    int tid = blockIdx.x * blockDim.x + threadIdx.x;
    int stride = gridDim.x * blockDim.x;
    float m = -3.402823466e38f;
    for (int i = tid; i < n4; i += stride) {
        float4 v = g4[i];
        m = fmaxf(m, fmaxf(fmaxf(v.x, v.y), fmaxf(v.z, v.w)));
    }
#pragma unroll
    for (int off = 32; off > 0; off >>= 1)
        m = fmaxf(m, __shfl_down(m, off));
    __shared__ float sm[4];
    if ((threadIdx.x & 63) == 0) sm[threadIdx.x >> 6] = m;
    __syncthreads();
    if (threadIdx.x == 0) {
        float mm = fmaxf(fmaxf(sm[0], sm[1]), fmaxf(sm[2], sm[3]));
        // no zero-init needed: 0xAA poison = enc(+3e-13), dominated by enc(max)
        atomicMax(ws_max, enc_f(mm));
    }
}

__device__ __forceinline__ float ssim_px(float sx, float sy, float sxx, float syy, float sxy,
                                         float C1, float C2) {
    const float inv49 = 1.0f / 49.0f;
    const float covn  = 49.0f / 48.0f;
    float ux  = sx * inv49, uy = sy * inv49;
    float uxx = sxx * inv49 - ux * ux;
    float uyy = syy * inv49 - uy * uy;
    float uxy = sxy * inv49 - ux * uy;
    float vvx = covn * uxx, vvy = covn * uyy, vvxy = covn * uxy;
    float num = (2.0f * ux * uy + C1) * (2.0f * vvxy + C2);
    float den = (ux * ux + uy * uy + C1) * (vvx + vvy + C2);
    return num / den;
}

__global__ void __launch_bounds__(BT)
ssim_kernel(const float* __restrict__ gt, const float* __restrict__ pred,
            const unsigned* __restrict__ ws_max, double* __restrict__ ws_part) {
    const int t    = threadIdx.x;
    const int tile = blockIdx.x;   // 0..2 column tiles (126 out cols each)
    const int band = blockIdx.y;   // 0..NBANDS-1
    const int b    = blockIdx.z;   // 0..63 images
    const int bid  = (b * NBANDS + band) * NTILES + tile;

    const int  row0   = band * BAND;
    const int  cbase2 = tile * 63;            // logical staged base (float2 units)
    const int  base2  = cbase2 & ~1;          // 16B-aligned staging base
    const int  off    = cbase2 & 1;           // uniform compute-index shift (0 or 1)
    // last valid 16B chunk offset within the row, from base2:
    const int  maxoff = W_ * 4 - base2 * 8 - 16;
    const bool active = (t < 63);             // thread t -> out cols tile*126+3+2t, +1

    // Whole band staged at once: 21 rows x 68 float2 (544B) x 2 arrays =
    // 22,848B -> 7 blocks/CU. Single vmcnt drain by construction.
    __shared__ __align__(16) float2 sg[SROWS][68], sp[SROWS][68];

    const float2* gbase = (const float2*)(gt   + (size_t)b * H_ * W_);
    const float2* pbase = (const float2*)(pred + (size_t)b * H_ * W_);

    // per-lane global byte offset (clamped so tile 2's lane 33 stays in-row;
    // its LDS slot idx 66..67 is never consumed by active lanes)
    const int laneoff = min(t * 16, maxoff);

    // ---- stage ALL rows up front: 42 async 16B-DMA instructions, then the
    // compiler inserts exactly ONE vmcnt wait before the first ds_read. ----
    if (t < 34) {   // 34 lanes x 16B = 544B = one whole row buffer per instr
#pragma unroll
        for (int r = 0; r < SROWS; ++r) {
            const int ir = min(row0 + r, H_ - 1);
            const char* grb = (const char*)(gbase + (size_t)ir * W2 + base2);
            const char* prb = (const char*)(pbase + (size_t)ir * W2 + base2);
            glds16(grb + laneoff, &sg[r][0]);   // lds dest: uniform row base
            glds16(prb + laneoff, &sp[r][0]);
        }
    }

    // C1/C2 scalar load issued after the DMAs so its latency overlaps them
    const float dr = dec_f(*ws_max);
    const float C1 = (0.01f * dr) * (0.01f * dr);
    const float C2 = (0.03f * dr) * (0.03f * dr);

    // vertical ring of horizontal 7-tap sums (2 columns packed in float2)
    float2 rx[7], ry[7], rxx[7], ryy[7], rxy[7];
#pragma unroll
    for (int j = 0; j < 7; ++j) {
        rx[j] = make_float2(0.f, 0.f); ry[j] = rx[j];
        rxx[j] = rx[j]; ryy[j] = rx[j]; rxy[j] = rx[j];
    }
    float2 vx = make_float2(0.f, 0.f), vy = vx, vxx = vx, vyy = vx, vxy = vx;
    double acc = 0.0;

    // ---- compute sweep: 3 groups x 7 rows; ring slot = j (compile-time,
    // rule #20); row index i = g*7+j is runtime in g -> LDS addr only. ----
#pragma unroll 1
    for (int g = 0; g < 3; ++g) {
#pragma unroll
        for (int j = 0; j < 7; ++j) {
            const int i  = g * 7 + j;      // staged-row index
            const int ti = t + off;
            const float2* rg = sg[i];
            const float2* rp = sp[i];
            // 8 taps (4 float2) covering both columns' 7-tap windows
            float2 d0 = rg[ti], d1 = rg[ti + 1], d2 = rg[ti + 2], d3 = rg[ti + 3];
            float2 e0 = rp[ti], e1 = rp[ti + 1], e2 = rp[ti + 2], e3 = rp[ti + 3];

            float hx0 = d0.x + d0.y + d1.x + d1.y + d2.x + d2.y + d3.x;
            float hy0 = e0.x + e0.y + e1.x + e1.y + e2.x + e2.y + e3.x;
            float hxx0 = fmaf(d0.x, d0.x, fmaf(d0.y, d0.y, fmaf(d1.x, d1.x,
                         fmaf(d1.y, d1.y, fmaf(d2.x, d2.x, fmaf(d2.y, d2.y, d3.x * d3.x))))));
            float hyy0 = fmaf(e0.x, e0.x, fmaf(e0.y, e0.y, fmaf(e1.x, e1.x,
                         fmaf(e1.y, e1.y, fmaf(e2.x, e2.x, fmaf(e2.y, e2.y, e3.x * e3.x))))));
            float hxy0 = fmaf(d0.x, e0.x, fmaf(d0.y, e0.y, fmaf(d1.x, e1.x,
                         fmaf(d1.y, e1.y, fmaf(d2.x, e2.x, fmaf(d2.y, e2.y, d3.x * e3.x))))));

            // horizontal slide for the second column: -tap0 +tap7
            float2 h_x  = make_float2(hx0,  hx0  - d0.x        + d3.y);
            float2 h_y  = make_float2(hy0,  hy0  - e0.x        + e3.y);
            float2 h_xx = make_float2(hxx0, hxx0 - d0.x * d0.x + d3.y * d3.y);
            float2 h_yy = make_float2(hyy0, hyy0 - e0.x * e0.x + e3.y * e3.y);
            float2 h_xy = make_float2(hxy0, hxy0 - d0.x * e0.x + d3.y * e3.y);

            // vertical sliding window: evict slot j (holds row i-7), insert row i
            vx  = f2add(vx,  f2sub(h_x,  rx[j]));  rx[j]  = h_x;
            vy  = f2add(vy,  f2sub(h_y,  ry[j]));  ry[j]  = h_y;
            vxx = f2add(vxx, f2sub(h_xx, rxx[j])); rxx[j] = h_xx;
            vyy = f2add(vyy, f2sub(h_yy, ryy[j])); ryy[j] = h_yy;
            vxy = f2add(vxy, f2sub(h_xy, rxy[j])); rxy[j] = h_xy;

            const int orow = row0 + i - 6;   // valid output rows: i >= 6
            if (i >= 6 && active && orow < OUTD) {
                acc += (double)ssim_px(vx.x, vy.x, vxx.x, vyy.x, vxy.x, C1, C2)
                     + (double)ssim_px(vx.y, vy.y, vxx.y, vyy.y, vxy.y, C1, C2);
            }
        }
    }

    // single-wave reduction (double) -> one plain store per block (no atomics)
#pragma unroll
    for (int off2 = 32; off2 > 0; off2 >>= 1)
        acc += __shfl_down(acc, off2);
    if (t == 0) ws_part[bid] = acc;
}

__global__ void __launch_bounds__(256)
final_kernel(const double* __restrict__ ws_part, float* __restrict__ out) {
    const int t = threadIdx.x;
    double s = 0.0;
    for (int i = t; i < TOTAL_BLOCKS; i += 256) s += ws_part[i];
#pragma unroll
    for (int off = 32; off > 0; off >>= 1)
        s += __shfl_down(s, off);
    __shared__ double sd[4];
    if ((t & 63) == 0) sd[t >> 6] = s;
    __syncthreads();
    if (t == 0) out[0] = (float)((sd[0] + sd[1] + sd[2] + sd[3]) / NPIX);
}

extern "C" void kernel_launch(void* const* d_in, const int* in_sizes, int n_in,
                              void* d_out, int out_size, void* d_ws, size_t ws_size,
                              hipStream_t stream) {
    const float* gt   = (const float*)d_in[0];
    const float* pred = (const float*)d_in[1];
    // d_in[2] is the uniform 1/49 window -> constant-folded into the kernel.
    float* out = (float*)d_out;

    unsigned* ws_max  = (unsigned*)d_ws;                   // offset 0 (4 B)
    double*   ws_part = (double*)((char*)d_ws + 64);       // 4992 doubles (~40 KB)

    // no memset: 0xAA poison is benign for atomicMax (enc-space +3e-13),
    // and ws_part is fully written by ssim_kernel before final_kernel reads.

    const int n4 = B_ * H_ * W_ / 4;  // 2,359,296 float4s
    max_kernel<<<1024, 256, 0, stream>>>((const float4*)gt, ws_max, n4);

    dim3 grid(NTILES, NBANDS, B_);    // col tiles x row bands x images
    ssim_kernel<<<grid, BT, 0, stream>>>(gt, pred, ws_max, ws_part);

    final_kernel<<<1, 256, 0, stream>>>(ws_part, out);
}

// Round 4
// 141.089 us; speedup vs baseline: 1.0285x; 1.0285x over previous
//
#include <hip/hip_runtime.h>

// SSIM (7x7 uniform window) over B=64, C=1, H=W=384 fp32 images.
// out = mean over interior 378x378 crop of all 64 images (scalar).
//
// R16 = NO-LDS direct-tap kernel. R15 counters: ssim 43.5us, VALUBusy 46%
// (-> 20us VALU busy-time = true floor), Occupancy 13.8% (~1.1 wave/SIMD:
// the 23KB LDS slab per single-wave block strangles TLP), HBM 20%, bank
// conflicts 0. Three staging structures (R12/R14/R15) all ~43us -> staging
// IS the bottleneck. Fix: drop LDS entirely; each thread loads its 8 taps
// (2 x 32B contiguous, stride-8B across lanes = perfectly coalesced
// dwordx2s; 4x tap overlap absorbed by L1/L2 same-line hits).
//   - LDS 23040 -> 0: occupancy VGPR-bound ~5 waves/SIMD (4.5x TLP).
//   - per-row stall (<=200cy L2) < 4x per-row compute (~300cy) -> VALU
//     saturates via TLP; no explicit pipelining needed.
//   - ssim_px rescaled by 49^4 (exact same value, ~11 fewer instr/px).
// Grid unchanged: 3 tiles x 26 bands x 64 imgs = 4992 single-wave blocks.
//
// K1 max_kernel: max(gt) -> ws_max (monotone-encoded uint, atomicMax)
// K2 ssim_kernel: 4992 single-wave blocks, direct global taps, no LDS
// K3 final_kernel: sum partials, divide, store d_out[0]
//
// BANNED (measured): LDS tap staging in ANY schedule (R12/R14/R15, all
// ~43us, occupancy-capped); coop grid.sync fusion (R13, +192us latency
// collapse); 12B global_load_lds (R10, absmax 0.21); VGPR cap via
// launch_bounds min-waves (R4, 33MB spill); per-block __threadfence
// finalize (R3/R5 VALU collapse); scalar 1col/thread taps (R8).

#define PADW 3
#define BT 64             // threads per block (1 wave); 63 compute 2 cols each
#define BAND 15           // output rows per block
#define SROWS (BAND + 6)  // 21 swept rows = 3 x 7

constexpr int B_ = 64, H_ = 384, W_ = 384;
constexpr int W2 = W_ / 2;                                // row length in float2
constexpr int OUTD = W_ - 2 * PADW;                       // 378
constexpr int NBANDS = (OUTD + BAND - 1) / BAND;          // 26
constexpr int NTILES = 3;                                 // 3 x 126 cols = 378
constexpr int TOTAL_BLOCKS = NTILES * NBANDS * B_;        // 4992
constexpr double NPIX = (double)B_ * OUTD * OUTD;         // 9,144,576

__device__ __forceinline__ unsigned enc_f(float f) {
    unsigned u = __float_as_uint(f);
    return (u & 0x80000000u) ? ~u : (u | 0x80000000u);
}
__device__ __forceinline__ float dec_f(unsigned e) {
    return __uint_as_float((e & 0x80000000u) ? (e & 0x7fffffffu) : ~e);
}

__device__ __forceinline__ float2 f2add(float2 a, float2 b) { return make_float2(a.x + b.x, a.y + b.y); }
__device__ __forceinline__ float2 f2sub(float2 a, float2 b) { return make_float2(a.x - b.x, a.y - b.y); }

__global__ void __launch_bounds__(256)
max_kernel(const float4* __restrict__ g4, unsigned* ws_max, int n4) {
    int tid = blockIdx.x * blockDim.x + threadIdx.x;
    int stride = gridDim.x * blockDim.x;
    float m = -3.402823466e38f;
    for (int i = tid; i < n4; i += stride) {
        float4 v = g4[i];
        m = fmaxf(m, fmaxf(fmaxf(v.x, v.y), fmaxf(v.z, v.w)));
    }
#pragma unroll
    for (int off = 32; off > 0; off >>= 1)
        m = fmaxf(m, __shfl_down(m, off));
    __shared__ float sm[4];
    if ((threadIdx.x & 63) == 0) sm[threadIdx.x >> 6] = m;
    __syncthreads();
    if (threadIdx.x == 0) {
        float mm = fmaxf(fmaxf(sm[0], sm[1]), fmaxf(sm[2], sm[3]));
        // no zero-init needed: 0xAA poison = enc(+3e-13), dominated by enc(max)
        atomicMax(ws_max, enc_f(mm));
    }
}

// 49^4-rescaled SSIM: multiply num and den of both factors by 49^2; the
// scale cancels in the ratio. Exactly the reference formula, fewer ops.
//   C1q = C1*2401, C2q = C2*2401, covn = 49/48
//   num = (2ab + C1q) * (2*covn*(49*sxy - ab) + C2q)
//   den = (a^2+b^2 + C1q) * (covn*(49*(sxx+syy) - (a^2+b^2)) + C2q)
__device__ __forceinline__ float ssim_px(float a, float b, float sxx, float syy, float sxy,
                                         float C1q, float C2q) {
    const float covn = 49.0f / 48.0f;
    float ab   = a * b;
    float num1 = fmaf(2.0f, ab, C1q);
    float txy  = fmaf(49.0f, sxy, -ab);
    float num2 = fmaf(2.0f * covn, txy, C2q);
    float b2   = b * b;
    float aabb = fmaf(a, a, b2);
    float den1 = aabb + C1q;
    float spq  = sxx + syy;
    float tv   = fmaf(49.0f, spq, -aabb);
    float den2 = fmaf(covn, tv, C2q);
    return (num1 * num2) / (den1 * den2);
}

__global__ void __launch_bounds__(BT)
ssim_kernel(const float* __restrict__ gt, const float* __restrict__ pred,
            const unsigned* __restrict__ ws_max, double* __restrict__ ws_part) {
    const int t    = threadIdx.x;
    const int tile = blockIdx.x;   // 0..2 column tiles (126 out cols each)
    const int band = blockIdx.y;   // 0..NBANDS-1
    const int b    = blockIdx.z;   // 0..63 images
    const int bid  = (b * NBANDS + band) * NTILES + tile;

    const float dr  = dec_f(*ws_max);
    const float c1  = 0.01f * dr, c2 = 0.03f * dr;
    const float C1q = c1 * c1 * 2401.0f;   // C1 * 49^2
    const float C2q = c2 * c2 * 2401.0f;   // C2 * 49^2

    const int  row0   = band * BAND;
    const bool active = (t < 63);  // thread t -> out cols tile*126+2t, +1

    // thread's tap base (float2 index in row): taps are [tb, tb+3], i.e.
    // floats 2*tb .. 2*tb+7 = the 8 cols covering both columns' 7-windows.
    // Clamp keeps lane 63 (inactive) in-row on tile 2 (189 -> 188).
    const int tb = min(tile * 63 + t, W2 - 4);

    const float2* gp = (const float2*)(gt   + (size_t)b * H_ * W_) + tb;
    const float2* pp = (const float2*)(pred + (size_t)b * H_ * W_) + tb;

    // vertical ring of horizontal 7-tap sums (2 columns packed in float2)
    float2 rx[7], ry[7], rxx[7], ryy[7], rxy[7];
#pragma unroll
    for (int j = 0; j < 7; ++j) {
        rx[j] = make_float2(0.f, 0.f); ry[j] = rx[j];
        rxx[j] = rx[j]; ryy[j] = rx[j]; rxy[j] = rx[j];
    }
    float2 vx = make_float2(0.f, 0.f), vy = vx, vxx = vx, vyy = vx, vxy = vx;
    double acc = 0.0;

    // ---- sweep 21 rows: 3 groups x 7 rows; ring slot = j (compile-time,
    // rule #20); taps loaded straight from global (coalesced dwordx2s). ----
#pragma unroll 1
    for (int g = 0; g < 3; ++g) {
#pragma unroll
        for (int j = 0; j < 7; ++j) {
            const int i  = g * 7 + j;                    // swept-row index
            const int ir = min(row0 + i, H_ - 1);        // clamped image row
            const float2* gr = gp + (size_t)ir * W2;
            const float2* pr = pp + (size_t)ir * W2;
            // 8 taps (4 float2) covering both columns' 7-tap windows
            float2 d0 = gr[0], d1 = gr[1], d2 = gr[2], d3 = gr[3];
            float2 e0 = pr[0], e1 = pr[1], e2 = pr[2], e3 = pr[3];

            float hx0 = d0.x + d0.y + d1.x + d1.y + d2.x + d2.y + d3.x;
            float hy0 = e0.x + e0.y + e1.x + e1.y + e2.x + e2.y + e3.x;
            float hxx0 = fmaf(d0.x, d0.x, fmaf(d0.y, d0.y, fmaf(d1.x, d1.x,
                         fmaf(d1.y, d1.y, fmaf(d2.x, d2.x, fmaf(d2.y, d2.y, d3.x * d3.x))))));
            float hyy0 = fmaf(e0.x, e0.x, fmaf(e0.y, e0.y, fmaf(e1.x, e1.x,
                         fmaf(e1.y, e1.y, fmaf(e2.x, e2.x, fmaf(e2.y, e2.y, e3.x * e3.x))))));
            float hxy0 = fmaf(d0.x, e0.x, fmaf(d0.y, e0.y, fmaf(d1.x, e1.x,
                         fmaf(d1.y, e1.y, fmaf(d2.x, e2.x, fmaf(d2.y, e2.y, d3.x * e3.x))))));

            // horizontal slide for the second column: -tap0 +tap7
            float2 h_x  = make_float2(hx0,  hx0  - d0.x        + d3.y);
            float2 h_y  = make_float2(hy0,  hy0  - e0.x        + e3.y);
            float2 h_xx = make_float2(hxx0, hxx0 - d0.x * d0.x + d3.y * d3.y);
            float2 h_yy = make_float2(hyy0, hyy0 - e0.x * e0.x + e3.y * e3.y);
            float2 h_xy = make_float2(hxy0, hxy0 - d0.x * e0.x + d3.y * e3.y);

            // vertical sliding window: evict slot j (holds row i-7), insert row i
            vx  = f2add(vx,  f2sub(h_x,  rx[j]));  rx[j]  = h_x;
            vy  = f2add(vy,  f2sub(h_y,  ry[j]));  ry[j]  = h_y;
            vxx = f2add(vxx, f2sub(h_xx, rxx[j])); rxx[j] = h_xx;
            vyy = f2add(vyy, f2sub(h_yy, ryy[j])); ryy[j] = h_yy;
            vxy = f2add(vxy, f2sub(h_xy, rxy[j])); rxy[j] = h_xy;

            const int orow = row0 + i - 6;   // valid output rows: i >= 6
            if (i >= 6 && active && orow < OUTD) {
                acc += (double)ssim_px(vx.x, vy.x, vxx.x, vyy.x, vxy.x, C1q, C2q)
                     + (double)ssim_px(vx.y, vy.y, vxx.y, vyy.y, vxy.y, C1q, C2q);
            }
        }
    }

    // single-wave reduction (double) -> one plain store per block (no atomics)
#pragma unroll
    for (int off2 = 32; off2 > 0; off2 >>= 1)
        acc += __shfl_down(acc, off2);
    if (t == 0) ws_part[bid] = acc;
}

__global__ void __launch_bounds__(256)
final_kernel(const double* __restrict__ ws_part, float* __restrict__ out) {
    const int t = threadIdx.x;
    double s = 0.0;
    for (int i = t; i < TOTAL_BLOCKS; i += 256) s += ws_part[i];
#pragma unroll
    for (int off = 32; off > 0; off >>= 1)
        s += __shfl_down(s, off);
    __shared__ double sd[4];
    if ((t & 63) == 0) sd[t >> 6] = s;
    __syncthreads();
    if (t == 0) out[0] = (float)((sd[0] + sd[1] + sd[2] + sd[3]) / NPIX);
}

extern "C" void kernel_launch(void* const* d_in, const int* in_sizes, int n_in,
                              void* d_out, int out_size, void* d_ws, size_t ws_size,
                              hipStream_t stream) {
    const float* gt   = (const float*)d_in[0];
    const float* pred = (const float*)d_in[1];
    // d_in[2] is the uniform 1/49 window -> constant-folded into the kernel.
    float* out = (float*)d_out;

    unsigned* ws_max  = (unsigned*)d_ws;                   // offset 0 (4 B)
    double*   ws_part = (double*)((char*)d_ws + 64);       // 4992 doubles (~40 KB)

    // no memset: 0xAA poison is benign for atomicMax (enc-space +3e-13),
    // and ws_part is fully written by ssim_kernel before final_kernel reads.

    const int n4 = B_ * H_ * W_ / 4;  // 2,359,296 float4s
    max_kernel<<<1024, 256, 0, stream>>>((const float4*)gt, ws_max, n4);

    dim3 grid(NTILES, NBANDS, B_);    // col tiles x row bands x images
    ssim_kernel<<<grid, BT, 0, stream>>>(gt, pred, ws_max, ws_part);

    final_kernel<<<1, 256, 0, stream>>>(ws_part, out);
}

// Round 5
// 135.312 us; speedup vs baseline: 1.0724x; 1.0427x over previous
//
#include <hip/hip_runtime.h>

// SSIM (7x7 uniform window) over B=64, C=1, H=W=384 fp32 images.
// out = mean over interior 378x378 crop of all 64 images (scalar).
//
// R17 = R16 (no-LDS direct-tap, 49^4-rescaled ssim_px) + REGISTER FIX +
// 4-wave workgroups. R16 evidence: VGPR_Count=68, but the algorithm's live
// state is ~115-130 (ring 5x7xfloat2 = 70, running sums 10, taps 32, addr/
// consts ~15) -> the ring has been SPILLED in every round (R12:96, R15:88,
// R16:68), putting scratch round-trips on the loop-carried v+=h-r[j] chain.
// That explains the structure-invariant ~42.5us ssim and pinned ~45%
// VALUBusy across 4 different staging schemes.
//   - __launch_bounds__(256, 2): VGPR budget 256 (no spill at ~130 live),
//     occupancy floor 2 waves/SIMD; headroom lets the compiler hoist
//     next-row tap loads (impossible at 68 regs).
//   - 256-thread blocks, wave w = band 4*blockIdx.y+w: grid (3,4,64) =
//     768 blocks x 4 waves = 3072 waves = 12/CU fully co-resident; BAND
//     24 / NBANDS 16 divides evenly (no idle waves) and cuts total
//     row-sweeps 105k -> 92k (-12% staging redundancy).
//   - sweep = 4 unrolled groups x 7 rows + 2-row tail (ring slots
//     compile-time: 28%7=0, 29%7=1; rule #20).
//
// K1 max_kernel: max(gt) -> ws_max (monotone-encoded uint, atomicMax)
// K2 ssim_kernel: 768 x 4-wave blocks, direct global taps, no LDS
// K3 final_kernel: sum partials, divide, store d_out[0]
//
// BANNED (measured): LDS tap staging in ANY schedule (R12/R14/R15, all
// ~43us); coop grid.sync fusion (R13, +192us latency collapse); 12B
// global_load_lds (R10, absmax 0.21); VGPR cap via HIGH min-waves
// launch_bounds (R4, 33MB spill -- R17 RAISES the budget instead);
// per-block __threadfence finalize (R3/R5); scalar 1col/thread taps (R8).

#define PADW 3
#define BT 256            // threads per block = 4 waves; wave w owns one band
#define WPB 4             // waves per block
#define BAND 24           // output rows per wave
#define SROWS (BAND + 6)  // 30 swept rows = 4 x 7 + 2

constexpr int B_ = 64, H_ = 384, W_ = 384;
constexpr int W2 = W_ / 2;                                // row length in float2
constexpr int OUTD = W_ - 2 * PADW;                       // 378
constexpr int NBANDS = 16;                                // 16 x 24 = 384 >= 378
constexpr int NBGRP  = NBANDS / WPB;                      // 4 band-groups
constexpr int NTILES = 3;                                 // 3 x 126 cols = 378
constexpr int TOTAL_PART = NTILES * NBANDS * B_;          // 3072 partials
constexpr double NPIX = (double)B_ * OUTD * OUTD;         // 9,144,576

__device__ __forceinline__ unsigned enc_f(float f) {
    unsigned u = __float_as_uint(f);
    return (u & 0x80000000u) ? ~u : (u | 0x80000000u);
}
__device__ __forceinline__ float dec_f(unsigned e) {
    return __uint_as_float((e & 0x80000000u) ? (e & 0x7fffffffu) : ~e);
}

__device__ __forceinline__ float2 f2add(float2 a, float2 b) { return make_float2(a.x + b.x, a.y + b.y); }
__device__ __forceinline__ float2 f2sub(float2 a, float2 b) { return make_float2(a.x - b.x, a.y - b.y); }

__global__ void __launch_bounds__(256)
max_kernel(const float4* __restrict__ g4, unsigned* ws_max, int n4) {
    int tid = blockIdx.x * blockDim.x + threadIdx.x;
    int stride = gridDim.x * blockDim.x;
    float m = -3.402823466e38f;
    for (int i = tid; i < n4; i += stride) {
        float4 v = g4[i];
        m = fmaxf(m, fmaxf(fmaxf(v.x, v.y), fmaxf(v.z, v.w)));
    }
#pragma unroll
    for (int off = 32; off > 0; off >>= 1)
        m = fmaxf(m, __shfl_down(m, off));
    __shared__ float sm[4];
    if ((threadIdx.x & 63) == 0) sm[threadIdx.x >> 6] = m;
    __syncthreads();
    if (threadIdx.x == 0) {
        float mm = fmaxf(fmaxf(sm[0], sm[1]), fmaxf(sm[2], sm[3]));
        // no zero-init needed: 0xAA poison = enc(+3e-13), dominated by enc(max)
        atomicMax(ws_max, enc_f(mm));
    }
}

// 49^4-rescaled SSIM: multiply num and den of both factors by 49^2; the
// scale cancels in the ratio. Exactly the reference formula, fewer ops.
__device__ __forceinline__ float ssim_px(float a, float b, float sxx, float syy, float sxy,
                                         float C1q, float C2q) {
    const float covn = 49.0f / 48.0f;
    float ab   = a * b;
    float num1 = fmaf(2.0f, ab, C1q);
    float txy  = fmaf(49.0f, sxy, -ab);
    float num2 = fmaf(2.0f * covn, txy, C2q);
    float b2   = b * b;
    float aabb = fmaf(a, a, b2);
    float den1 = aabb + C1q;
    float spq  = sxx + syy;
    float tv   = fmaf(49.0f, spq, -aabb);
    float den2 = fmaf(covn, tv, C2q);
    return (num1 * num2) / (den1 * den2);
}

__global__ void __launch_bounds__(BT, 2)
ssim_kernel(const float* __restrict__ gt, const float* __restrict__ pred,
            const unsigned* __restrict__ ws_max, double* __restrict__ ws_part) {
    const int t    = threadIdx.x;
    const int lane = t & 63;
    const int wave = t >> 6;               // 0..3
    const int tile = blockIdx.x;           // 0..2 column tiles (126 out cols)
    const int band = blockIdx.y * WPB + wave;   // 0..15, one band per wave
    const int b    = blockIdx.z;           // 0..63 images
    const int bid  = (b * NBANDS + band) * NTILES + tile;

    const float dr  = dec_f(*ws_max);
    const float c1  = 0.01f * dr, c2 = 0.03f * dr;
    const float C1q = c1 * c1 * 2401.0f;   // C1 * 49^2
    const float C2q = c2 * c2 * 2401.0f;   // C2 * 49^2

    const int  row0   = band * BAND;
    const bool active = (lane < 63);  // lane -> out cols tile*126+2*lane, +1

    // thread's tap base (float2 index in row): floats 2*tb .. 2*tb+7 cover
    // both columns' 7-tap windows. Clamp keeps lane 63 in-row on tile 2.
    const int tb = min(tile * 63 + lane, W2 - 4);

    const float2* gp = (const float2*)(gt   + (size_t)b * H_ * W_) + tb;
    const float2* pp = (const float2*)(pred + (size_t)b * H_ * W_) + tb;

    // vertical ring of horizontal 7-tap sums (2 columns packed in float2).
    // 5 x 7 x float2 = 70 VGPR live by design -- budget 256 fits it.
    float2 rx[7], ry[7], rxx[7], ryy[7], rxy[7];
#pragma unroll
    for (int j = 0; j < 7; ++j) {
        rx[j] = make_float2(0.f, 0.f); ry[j] = rx[j];
        rxx[j] = rx[j]; ryy[j] = rx[j]; rxy[j] = rx[j];
    }
    float2 vx = make_float2(0.f, 0.f), vy = vx, vxx = vx, vyy = vx, vxy = vx;
    double acc = 0.0;

    // one row of the sweep: loads taps, slides windows, emits output row i-6
    auto dorow = [&](int i, int slot) {
        const int ir = min(row0 + i, H_ - 1);        // clamped image row
        const float2* gr = gp + (size_t)ir * W2;
        const float2* pr = pp + (size_t)ir * W2;
        // 8 taps (4 float2) covering both columns' 7-tap windows
        float2 d0 = gr[0], d1 = gr[1], d2 = gr[2], d3 = gr[3];
        float2 e0 = pr[0], e1 = pr[1], e2 = pr[2], e3 = pr[3];

        float hx0 = d0.x + d0.y + d1.x + d1.y + d2.x + d2.y + d3.x;
        float hy0 = e0.x + e0.y + e1.x + e1.y + e2.x + e2.y + e3.x;
        float hxx0 = fmaf(d0.x, d0.x, fmaf(d0.y, d0.y, fmaf(d1.x, d1.x,
                     fmaf(d1.y, d1.y, fmaf(d2.x, d2.x, fmaf(d2.y, d2.y, d3.x * d3.x))))));
        float hyy0 = fmaf(e0.x, e0.x, fmaf(e0.y, e0.y, fmaf(e1.x, e1.x,
                     fmaf(e1.y, e1.y, fmaf(e2.x, e2.x, fmaf(e2.y, e2.y, e3.x * e3.x))))));
        float hxy0 = fmaf(d0.x, e0.x, fmaf(d0.y, e0.y, fmaf(d1.x, e1.x,
                     fmaf(d1.y, e1.y, fmaf(d2.x, e2.x, fmaf(d2.y, e2.y, d3.x * e3.x))))));

        // horizontal slide for the second column: -tap0 +tap7
        float2 h_x  = make_float2(hx0,  hx0  - d0.x        + d3.y);
        float2 h_y  = make_float2(hy0,  hy0  - e0.x        + e3.y);
        float2 h_xx = make_float2(hxx0, hxx0 - d0.x * d0.x + d3.y * d3.y);
        float2 h_yy = make_float2(hyy0, hyy0 - e0.x * e0.x + e3.y * e3.y);
        float2 h_xy = make_float2(hxy0, hxy0 - d0.x * e0.x + d3.y * e3.y);

        // vertical sliding window: evict slot (holds row i-7), insert row i
        vx  = f2add(vx,  f2sub(h_x,  rx[slot]));  rx[slot]  = h_x;
        vy  = f2add(vy,  f2sub(h_y,  ry[slot]));  ry[slot]  = h_y;
        vxx = f2add(vxx, f2sub(h_xx, rxx[slot])); rxx[slot] = h_xx;
        vyy = f2add(vyy, f2sub(h_yy, ryy[slot])); ryy[slot] = h_yy;
        vxy = f2add(vxy, f2sub(h_xy, rxy[slot])); rxy[slot] = h_xy;

        const int orow = row0 + i - 6;   // valid output rows: i >= 6
        if (i >= 6 && active && orow < OUTD) {
            acc += (double)ssim_px(vx.x, vy.x, vxx.x, vyy.x, vxy.x, C1q, C2q)
                 + (double)ssim_px(vx.y, vy.y, vxx.y, vyy.y, vxy.y, C1q, C2q);
        }
    };

    // sweep 30 rows: 4 groups x 7 (ring slot = j, compile-time) + 2-row tail
    // (slots 28%7=0, 29%7=1, compile-time). Rule #20 holds throughout.
#pragma unroll 1
    for (int g = 0; g < 4; ++g) {
#pragma unroll
        for (int j = 0; j < 7; ++j) dorow(g * 7 + j, j);
    }
    dorow(28, 0);
    dorow(29, 1);

    // per-wave reduction (double) -> one plain store per wave (no atomics)
#pragma unroll
    for (int off2 = 32; off2 > 0; off2 >>= 1)
        acc += __shfl_down(acc, off2);
    if (lane == 0) ws_part[bid] = acc;
}

__global__ void __launch_bounds__(256)
final_kernel(const double* __restrict__ ws_part, float* __restrict__ out) {
    const int t = threadIdx.x;
    double s = 0.0;
    for (int i = t; i < TOTAL_PART; i += 256) s += ws_part[i];
#pragma unroll
    for (int off = 32; off > 0; off >>= 1)
        s += __shfl_down(s, off);
    __shared__ double sd[4];
    if ((t & 63) == 0) sd[t >> 6] = s;
    __syncthreads();
    if (t == 0) out[0] = (float)((sd[0] + sd[1] + sd[2] + sd[3]) / NPIX);
}

extern "C" void kernel_launch(void* const* d_in, const int* in_sizes, int n_in,
                              void* d_out, int out_size, void* d_ws, size_t ws_size,
                              hipStream_t stream) {
    const float* gt   = (const float*)d_in[0];
    const float* pred = (const float*)d_in[1];
    // d_in[2] is the uniform 1/49 window -> constant-folded into the kernel.
    float* out = (float*)d_out;

    unsigned* ws_max  = (unsigned*)d_ws;                   // offset 0 (4 B)
    double*   ws_part = (double*)((char*)d_ws + 64);       // 3072 doubles (~24 KB)

    // no memset: 0xAA poison is benign for atomicMax (enc-space +3e-13),
    // and ws_part is fully written by ssim_kernel before final_kernel reads.

    const int n4 = B_ * H_ * W_ / 4;  // 2,359,296 float4s
    max_kernel<<<1024, 256, 0, stream>>>((const float4*)gt, ws_max, n4);

    dim3 grid(NTILES, NBGRP, B_);     // col tiles x band-groups x images
    ssim_kernel<<<grid, BT, 0, stream>>>(gt, pred, ws_max, ws_part);

    final_kernel<<<1, 256, 0, stream>>>(ws_part, out);
}

// Round 6
// 131.242 us; speedup vs baseline: 1.1056x; 1.0310x over previous
//
#include <hip/hip_runtime.h>

// SSIM (7x7 uniform window) over B=64, C=1, H=W=384 fp32 images.
// out = mean over interior 378x378 crop of all 64 images (scalar).
//
// R18 = R17 (no-LDS direct-tap, 4-wave blocks, BAND 24) + occupancy pin +
// VALU trims. R16 post-mortem: WRITE_SIZE=157KB refutes scratch spill; at
// VGPR=68 the ring lived in AGPRs (unified file, accvgpr moves) -> R17's
// budget raise recovered only the mov overhead (~6us). Remaining stall:
// per-wave VALU duty ~27% (VALUBusy 45% / 1.65 waves/SIMD) -- memory
// latency on the per-row chain with only ~2 waves/SIMD resident (combined
// VGPR+AGPR ~138 > 128). Fixes:
//   - __launch_bounds__(256, 3): combined reg cap 170 (512/3) >= live ~130
//     -> no AGPR shuffling, 3 waves/SIMD guaranteed -> the whole 3072-wave
//     grid (12 waves/CU) co-resident in ONE batch, ~40 spare regs for the
//     scheduler to hoist next-row tap loads. (Distinct from R4's ban: that
//     capped BELOW the live set -> 33MB scratch; 170 is above it.)
//   - fused divide: s1+s2 = (na*db+nb*da)/(da*db), one IEEE div/row not two.
//   - float per-thread/wave accumulation (double only at partial store);
//     error ~1e-9 on final mean (random-walk over 196k thread sums).
//
// K1 max_kernel: max(gt) -> ws_max (monotone-encoded uint, atomicMax)
// K2 ssim_kernel: 768 x 4-wave blocks, direct global taps, no LDS
// K3 final_kernel: sum partials, divide, store d_out[0]
//
// BANNED (measured): LDS tap staging in ANY schedule (R12/R14/R15, all
// ~43us); coop grid.sync fusion (R13, +192us latency collapse); 12B
// global_load_lds (R10, absmax 0.21); launch_bounds cap BELOW live set
// (R4, 33MB spill); per-block __threadfence finalize (R3/R5); scalar
// 1col/thread taps via LDS (R8).

#define PADW 3
#define BT 256            // threads per block = 4 waves; wave w owns one band
#define WPB 4             // waves per block
#define BAND 24           // output rows per wave
#define SROWS (BAND + 6)  // 30 swept rows = 4 x 7 + 2

constexpr int B_ = 64, H_ = 384, W_ = 384;
constexpr int W2 = W_ / 2;                                // row length in float2
constexpr int OUTD = W_ - 2 * PADW;                       // 378
constexpr int NBANDS = 16;                                // 16 x 24 = 384 >= 378
constexpr int NBGRP  = NBANDS / WPB;                      // 4 band-groups
constexpr int NTILES = 3;                                 // 3 x 126 cols = 378
constexpr int TOTAL_PART = NTILES * NBANDS * B_;          // 3072 partials
constexpr double NPIX = (double)B_ * OUTD * OUTD;         // 9,144,576

__device__ __forceinline__ unsigned enc_f(float f) {
    unsigned u = __float_as_uint(f);
    return (u & 0x80000000u) ? ~u : (u | 0x80000000u);
}
__device__ __forceinline__ float dec_f(unsigned e) {
    return __uint_as_float((e & 0x80000000u) ? (e & 0x7fffffffu) : ~e);
}

__device__ __forceinline__ float2 f2add(float2 a, float2 b) { return make_float2(a.x + b.x, a.y + b.y); }
__device__ __forceinline__ float2 f2sub(float2 a, float2 b) { return make_float2(a.x - b.x, a.y - b.y); }

__global__ void __launch_bounds__(256)
max_kernel(const float4* __restrict__ g4, unsigned* ws_max, int n4) {
    int tid = blockIdx.x * blockDim.x + threadIdx.x;
    int stride = gridDim.x * blockDim.x;
    float m = -3.402823466e38f;
    for (int i = tid; i < n4; i += stride) {
        float4 v = g4[i];
        m = fmaxf(m, fmaxf(fmaxf(v.x, v.y), fmaxf(v.z, v.w)));
    }
#pragma unroll
    for (int off = 32; off > 0; off >>= 1)
        m = fmaxf(m, __shfl_down(m, off));
    __shared__ float sm[4];
    if ((threadIdx.x & 63) == 0) sm[threadIdx.x >> 6] = m;
    __syncthreads();
    if (threadIdx.x == 0) {
        float mm = fmaxf(fmaxf(sm[0], sm[1]), fmaxf(sm[2], sm[3]));
        // no zero-init needed: 0xAA poison = enc(+3e-13), dominated by enc(max)
        atomicMax(ws_max, enc_f(mm));
    }
}

// 49^4-rescaled SSIM numerator/denominator products (scale cancels in the
// ratio; exactly the reference formula).
__device__ __forceinline__ void ssim_nd(float a, float b, float sxx, float syy, float sxy,
                                        float C1q, float C2q, float& num, float& den) {
    const float covn = 49.0f / 48.0f;
    float ab   = a * b;
    float num1 = fmaf(2.0f, ab, C1q);
    float txy  = fmaf(49.0f, sxy, -ab);
    float num2 = fmaf(2.0f * covn, txy, C2q);
    float b2   = b * b;
    float aabb = fmaf(a, a, b2);
    float den1 = aabb + C1q;
    float spq  = sxx + syy;
    float tv   = fmaf(49.0f, spq, -aabb);
    float den2 = fmaf(covn, tv, C2q);
    num = num1 * num2;
    den = den1 * den2;
}

__global__ void __launch_bounds__(BT, 3)
ssim_kernel(const float* __restrict__ gt, const float* __restrict__ pred,
            const unsigned* __restrict__ ws_max, double* __restrict__ ws_part) {
    const int t    = threadIdx.x;
    const int lane = t & 63;
    const int wave = t >> 6;               // 0..3
    const int tile = blockIdx.x;           // 0..2 column tiles (126 out cols)
    const int band = blockIdx.y * WPB + wave;   // 0..15, one band per wave
    const int b    = blockIdx.z;           // 0..63 images
    const int bid  = (b * NBANDS + band) * NTILES + tile;

    const float dr  = dec_f(*ws_max);
    const float c1  = 0.01f * dr, c2 = 0.03f * dr;
    const float C1q = c1 * c1 * 2401.0f;   // C1 * 49^2
    const float C2q = c2 * c2 * 2401.0f;   // C2 * 49^2

    const int  row0   = band * BAND;
    const bool active = (lane < 63);  // lane -> out cols tile*126+2*lane, +1

    // thread's tap base (float2 index in row): floats 2*tb .. 2*tb+7 cover
    // both columns' 7-tap windows. Clamp keeps lane 63 in-row on tile 2.
    const int tb = min(tile * 63 + lane, W2 - 4);

    const float2* gp = (const float2*)(gt   + (size_t)b * H_ * W_) + tb;
    const float2* pp = (const float2*)(pred + (size_t)b * H_ * W_) + tb;

    // vertical ring of horizontal 7-tap sums (2 columns packed in float2).
    // 5 x 7 x float2 = 70 VGPR live by design -- cap 170 fits it + headroom.
    float2 rx[7], ry[7], rxx[7], ryy[7], rxy[7];
#pragma unroll
    for (int j = 0; j < 7; ++j) {
        rx[j] = make_float2(0.f, 0.f); ry[j] = rx[j];
        rxx[j] = rx[j]; ryy[j] = rx[j]; rxy[j] = rx[j];
    }
    float2 vx = make_float2(0.f, 0.f), vy = vx, vxx = vx, vyy = vx, vxy = vx;
    float acc = 0.0f;   // per-thread sum <= 48; double only at partial store

    // one row of the sweep: loads taps, slides windows, emits output row i-6
    auto dorow = [&](int i, int slot) {
        const int ir = min(row0 + i, H_ - 1);        // clamped image row
        const float2* gr = gp + (size_t)ir * W2;
        const float2* pr = pp + (size_t)ir * W2;
        // 8 taps (4 float2) covering both columns' 7-tap windows
        float2 d0 = gr[0], d1 = gr[1], d2 = gr[2], d3 = gr[3];
        float2 e0 = pr[0], e1 = pr[1], e2 = pr[2], e3 = pr[3];

        float hx0 = d0.x + d0.y + d1.x + d1.y + d2.x + d2.y + d3.x;
        float hy0 = e0.x + e0.y + e1.x + e1.y + e2.x + e2.y + e3.x;
        float hxx0 = fmaf(d0.x, d0.x, fmaf(d0.y, d0.y, fmaf(d1.x, d1.x,
                     fmaf(d1.y, d1.y, fmaf(d2.x, d2.x, fmaf(d2.y, d2.y, d3.x * d3.x))))));
        float hyy0 = fmaf(e0.x, e0.x, fmaf(e0.y, e0.y, fmaf(e1.x, e1.x,
                     fmaf(e1.y, e1.y, fmaf(e2.x, e2.x, fmaf(e2.y, e2.y, e3.x * e3.x))))));
        float hxy0 = fmaf(d0.x, e0.x, fmaf(d0.y, e0.y, fmaf(d1.x, e1.x,
                     fmaf(d1.y, e1.y, fmaf(d2.x, e2.x, fmaf(d2.y, e2.y, d3.x * e3.x))))));

        // horizontal slide for the second column: -tap0 +tap7
        float2 h_x  = make_float2(hx0,  hx0  - d0.x        + d3.y);
        float2 h_y  = make_float2(hy0,  hy0  - e0.x        + e3.y);
        float2 h_xx = make_float2(hxx0, hxx0 - d0.x * d0.x + d3.y * d3.y);
        float2 h_yy = make_float2(hyy0, hyy0 - e0.x * e0.x + e3.y * e3.y);
        float2 h_xy = make_float2(hxy0, hxy0 - d0.x * e0.x + d3.y * e3.y);

        // vertical sliding window: evict slot (holds row i-7), insert row i
        vx  = f2add(vx,  f2sub(h_x,  rx[slot]));  rx[slot]  = h_x;
        vy  = f2add(vy,  f2sub(h_y,  ry[slot]));  ry[slot]  = h_y;
        vxx = f2add(vxx, f2sub(h_xx, rxx[slot])); rxx[slot] = h_xx;
        vyy = f2add(vyy, f2sub(h_yy, ryy[slot])); ryy[slot] = h_yy;
        vxy = f2add(vxy, f2sub(h_xy, rxy[slot])); rxy[slot] = h_xy;

        const int orow = row0 + i - 6;   // valid output rows: i >= 6
        if (i >= 6 && active && orow < OUTD) {
            float na, da, nb, db;
            ssim_nd(vx.x, vy.x, vxx.x, vyy.x, vxy.x, C1q, C2q, na, da);
            ssim_nd(vx.y, vy.y, vxx.y, vyy.y, vxy.y, C1q, C2q, nb, db);
            // s1 + s2 = (na*db + nb*da) / (da*db): one divide per row
            acc += fmaf(na, db, nb * da) / (da * db);
        }
    };

    // sweep 30 rows: 4 groups x 7 (ring slot = j, compile-time) + 2-row tail
    // (slots 28%7=0, 29%7=1, compile-time). Rule #20 holds throughout.
#pragma unroll 1
    for (int g = 0; g < 4; ++g) {
#pragma unroll
        for (int j = 0; j < 7; ++j) dorow(g * 7 + j, j);
    }
    dorow(28, 0);
    dorow(29, 1);

    // per-wave reduction (float) -> one double store per wave (no atomics)
#pragma unroll
    for (int off2 = 32; off2 > 0; off2 >>= 1)
        acc += __shfl_down(acc, off2);
    if (lane == 0) ws_part[bid] = (double)acc;
}

__global__ void __launch_bounds__(256)
final_kernel(const double* __restrict__ ws_part, float* __restrict__ out) {
    const int t = threadIdx.x;
    double s = 0.0;
    for (int i = t; i < TOTAL_PART; i += 256) s += ws_part[i];
#pragma unroll
    for (int off = 32; off > 0; off >>= 1)
        s += __shfl_down(s, off);
    __shared__ double sd[4];
    if ((t & 63) == 0) sd[t >> 6] = s;
    __syncthreads();
    if (t == 0) out[0] = (float)((sd[0] + sd[1] + sd[2] + sd[3]) / NPIX);
}

extern "C" void kernel_launch(void* const* d_in, const int* in_sizes, int n_in,
                              void* d_out, int out_size, void* d_ws, size_t ws_size,
                              hipStream_t stream) {
    const float* gt   = (const float*)d_in[0];
    const float* pred = (const float*)d_in[1];
    // d_in[2] is the uniform 1/49 window -> constant-folded into the kernel.
    float* out = (float*)d_out;

    unsigned* ws_max  = (unsigned*)d_ws;                   // offset 0 (4 B)
    double*   ws_part = (double*)((char*)d_ws + 64);       // 3072 doubles (~24 KB)

    // no memset: 0xAA poison is benign for atomicMax (enc-space +3e-13),
    // and ws_part is fully written by ssim_kernel before final_kernel reads.

    const int n4 = B_ * H_ * W_ / 4;  // 2,359,296 float4s
    max_kernel<<<1024, 256, 0, stream>>>((const float4*)gt, ws_max, n4);

    dim3 grid(NTILES, NBGRP, B_);     // col tiles x band-groups x images
    ssim_kernel<<<grid, BT, 0, stream>>>(gt, pred, ws_max, ws_part);

    final_kernel<<<1, 256, 0, stream>>>(ws_part, out);
}